// Round 10
// baseline (226.460 us; speedup 1.0000x reference)
//
#include <hip/hip_runtime.h>
#include <math.h>

typedef unsigned short u16;
typedef __attribute__((ext_vector_type(8))) _Float16 half8;    // 8 fp16
typedef __attribute__((ext_vector_type(4))) float    f32x4;

#define BATCH 4
#define NPB   4096      // pixels per batch (H*W)
#define BN    16384     // BATCH * NPB
#define CC    256       // input channels
#define D     128       // output channels (C/2)
#define LOG2E 1.44269504088896f

#if __has_builtin(__builtin_amdgcn_exp2f)
#define EXP2(x) __builtin_amdgcn_exp2f(x)
#else
#define EXP2(x) exp2f(x)
#endif

// wait lgkmcnt(0) only (vmcnt=63, expcnt=7 -> no VMEM fence, loads stay in flight)
#define WAIT_LDS() __builtin_amdgcn_s_waitcnt(0xC07F)

// 16-lane (DPP row) reductions on the VALU pipe — no LDS crossbar.
template<int CTRL>
__device__ __forceinline__ float dpp_mov(float x) {
    return __builtin_bit_cast(float, __builtin_amdgcn_update_dpp(
        __builtin_bit_cast(int, x), __builtin_bit_cast(int, x),
        CTRL, 0xf, 0xf, false));
}
__device__ __forceinline__ float dpp_row_max(float x) {
    x = fmaxf(x, dpp_mov<0x128>(x));   // row_ror:8
    x = fmaxf(x, dpp_mov<0x124>(x));   // row_ror:4
    x = fmaxf(x, dpp_mov<0x122>(x));   // row_ror:2
    x = fmaxf(x, dpp_mov<0x121>(x));   // row_ror:1
    return x;
}
__device__ __forceinline__ float dpp_row_sum(float x) {
    x += dpp_mov<0x128>(x);
    x += dpp_mov<0x124>(x);
    x += dpp_mov<0x122>(x);
    x += dpp_mov<0x121>(x);
    return x;
}

// ---------------------------------------------------------------------------
// Prep: W[mat] (f32 [256][128]) -> Wt[mat][c][k] fp16 (c-major, contiguous k).
// mat 0 (K) pre-scaled by log2e. 128 blocks x 256 threads x 4 elements.
// ---------------------------------------------------------------------------
__global__ __launch_bounds__(256) void prep_kernel(
    const float* __restrict__ Wk, const float* __restrict__ Wq,
    const float* __restrict__ Wv, const float* __restrict__ Ws,
    u16* __restrict__ Wt)
{
    const int f   = (blockIdx.x * 256 + threadIdx.x) * 4;   // flat output idx
    const int mat = f >> 15;
    const int rem = f & 32767;
    const int c   = rem >> 8;
    const int k0  = rem & 255;
    const float* W = (mat == 0) ? Wk : (mat == 1) ? Wq : (mat == 2) ? Wv : Ws;
    const float scale = (mat == 0) ? LOG2E : 1.0f;
    _Float16 t4[4];
#pragma unroll
    for (int i = 0; i < 4; ++i)
        t4[i] = (_Float16)(W[(size_t)(k0 + i) * D + c] * scale);
    *(uint2*)&Wt[(size_t)mat * 32768 + (size_t)c * 256 + k0] = *(const uint2*)t4;
}

// ---------------------------------------------------------------------------
// Projection, LDS-free (unchanged from round 9): 512 blocks x 32 pixels,
// each block computes all four matrices; fragments direct from global.
// ---------------------------------------------------------------------------
__global__ __launch_bounds__(256) void proj_kernel(
    const float* __restrict__ x, const u16* __restrict__ Wt,
    const float* __restrict__ bk, const float* __restrict__ bq,
    const float* __restrict__ bv, const float* __restrict__ bs,
    u16* __restrict__ Kh, u16* __restrict__ Qh,
    u16* __restrict__ Vt, float* __restrict__ Sc)
{
    const int tid = threadIdx.x;
    const int wv  = tid >> 6;
    const int l   = tid & 63;
    const int l15 = l & 15;
    const int l4  = l >> 4;
    const int gm0 = blockIdx.x * 32;
    const int c0  = wv * 32;

    // ---- x fragments: xf[mt][kc], lane -> x[pixel=gm0+mt*16+l15][k=kc*32+l4*8..+8]
    half8 xf[2][8];
#pragma unroll
    for (int mt = 0; mt < 2; ++mt) {
        const float* xr = x + (size_t)(gm0 + mt * 16 + l15) * CC + l4 * 8;
#pragma unroll
        for (int kc = 0; kc < 8; ++kc) {
            const float4 a = ((const float4*)(xr + kc * 32))[0];
            const float4 b = ((const float4*)(xr + kc * 32))[1];
            xf[mt][kc] = (half8){(_Float16)a.x, (_Float16)a.y, (_Float16)a.z,
                                 (_Float16)a.w, (_Float16)b.x, (_Float16)b.y,
                                 (_Float16)b.z, (_Float16)b.w};
        }
    }

#pragma unroll
    for (int mat = 0; mat < 4; ++mat) {
        const u16* wb = Wt + (size_t)mat * 32768 + (size_t)(c0 + l15) * 256 + l4 * 8;
        half8 wf[2][8];
#pragma unroll
        for (int ct = 0; ct < 2; ++ct)
#pragma unroll
            for (int kc = 0; kc < 8; ++kc)
                wf[ct][kc] = *(const half8*)(wb + ct * 16 * 256 + kc * 32);

        f32x4 acc[2][2];
#pragma unroll
        for (int mt = 0; mt < 2; ++mt)
#pragma unroll
            for (int ct = 0; ct < 2; ++ct)
                acc[mt][ct] = (f32x4){0.f, 0.f, 0.f, 0.f};

#pragma unroll
        for (int kc = 0; kc < 8; ++kc)
#pragma unroll
            for (int mt = 0; mt < 2; ++mt)
#pragma unroll
                for (int ct = 0; ct < 2; ++ct) {
                    if (mat == 2)   // V: D[m][c] (packed transposed stores)
                        acc[mt][ct] = __builtin_amdgcn_mfma_f32_16x16x32_f16(
                            xf[mt][kc], wf[ct][kc], acc[mt][ct], 0, 0, 0);
                    else            // K/Q/Sc: D[c][m] (packed row stores)
                        acc[mt][ct] = __builtin_amdgcn_mfma_f32_16x16x32_f16(
                            wf[ct][kc], xf[mt][kc], acc[mt][ct], 0, 0, 0);
                }

        if (mat == 2) {
            const float bb[2] = {bv[c0 + l15], bv[c0 + 16 + l15]};
            const int batch = gm0 >> 12;
            const int mb0   = (gm0 & 4095) + l4 * 4;
            u16* vbp = Vt + (size_t)batch * (D * NPB);
#pragma unroll
            for (int mt = 0; mt < 2; ++mt)
#pragma unroll
                for (int ct = 0; ct < 2; ++ct) {
                    const int c = c0 + ct * 16 + l15;
                    _Float16 t4[4];
#pragma unroll
                    for (int r = 0; r < 4; ++r)
                        t4[r] = (_Float16)(acc[mt][ct][r] + bb[ct]);
                    *(uint2*)&vbp[(size_t)c * NPB + mb0 + mt * 16] =
                        *(const uint2*)t4;
                }
        } else if (mat == 3) {
            float bb2[2][4];
#pragma unroll
            for (int ct = 0; ct < 2; ++ct)
#pragma unroll
                for (int r = 0; r < 4; ++r)
                    bb2[ct][r] = bs[c0 + ct * 16 + l4 * 4 + r];
#pragma unroll
            for (int mt = 0; mt < 2; ++mt) {
                const int m = gm0 + mt * 16 + l15;
#pragma unroll
                for (int ct = 0; ct < 2; ++ct) {
                    float4 v;
                    v.x = acc[mt][ct][0] + bb2[ct][0];
                    v.y = acc[mt][ct][1] + bb2[ct][1];
                    v.z = acc[mt][ct][2] + bb2[ct][2];
                    v.w = acc[mt][ct][3] + bb2[ct][3];
                    *(float4*)&Sc[(size_t)m * D + c0 + ct * 16 + l4 * 4] = v;
                }
            }
        } else {
            const float* bsrc = (mat == 0) ? bk : bq;
            const float scale = (mat == 0) ? LOG2E : 1.0f;
            u16* O = (mat == 0) ? Kh : Qh;
            float bb2[2][4];
#pragma unroll
            for (int ct = 0; ct < 2; ++ct)
#pragma unroll
                for (int r = 0; r < 4; ++r)
                    bb2[ct][r] = bsrc[c0 + ct * 16 + l4 * 4 + r] * scale;
#pragma unroll
            for (int mt = 0; mt < 2; ++mt) {
                const int m = gm0 + mt * 16 + l15;
#pragma unroll
                for (int ct = 0; ct < 2; ++ct) {
                    _Float16 t4[4];
#pragma unroll
                    for (int r = 0; r < 4; ++r)
                        t4[r] = (_Float16)(acc[mt][ct][r] + bb2[ct][r]);
                    *(uint2*)&O[(size_t)m * D + c0 + ct * 16 + l4 * 4] =
                        *(const uint2*)t4;
                }
            }
        }
    }
}

// ---------------------------------------------------------------------------
// Flash attention, barrier-free K-loop, direct-from-global fragments.
// 512 blocks x 32 n-rows; 4 waves = 4 m-quarters (1024 m each, TM=32);
// each wave computes BOTH 16-row n-groups (reuses qf/vf across them).
// Only the P transpose (wave-private) + final combine use LDS.
// K pre-scaled by log2e -> exp2-domain online softmax, DPP reductions.
// ---------------------------------------------------------------------------
#define VP 40           // Ps row pitch (u16)

__global__ __launch_bounds__(256, 2) void attn_kernel(
    const u16* __restrict__ Kh, const u16* __restrict__ Qh,
    const u16* __restrict__ Vt, const float* __restrict__ Sc,
    float* __restrict__ out)
{
    __shared__ __align__(16) unsigned char smem[60416];
    u16 (*Ps)[2][16][VP]    = (u16(*)[2][16][VP])(smem);          // 4w x 2ng (10240 B)
    float (*Obuf)[2][16][D] = (float(*)[2][16][D])(smem + 10240); // 3w x 2ng (49152 B)
    float* cmbM = (float*)(smem + 59392);                         // 8 x 16
    float* cmbL = (float*)(smem + 59904);                         // 8 x 16

    const int tid = threadIdx.x;
    const int wv  = tid >> 6;               // m-quarter
    const int l   = tid & 63;
    const int l15 = l & 15;
    const int l4  = l >> 4;
    const int batch = blockIdx.x >> 7;      // consecutive blocks share batch (L2)
    const int tile  = blockIdx.x & 127;
    const int gr0   = batch * NPB + tile * 32;

    // ---- K fragments from global: kf[kc][ng], rows gr0 + ng*16 + l15
    half8 kf[4][2];
#pragma unroll
    for (int ng = 0; ng < 2; ++ng) {
        const u16* kb = Kh + (size_t)(gr0 + ng * 16 + l15) * D + l4 * 8;
#pragma unroll
        for (int kc = 0; kc < 4; ++kc)
            kf[kc][ng] = *(const half8*)(kb + kc * 32);
    }

    f32x4 Oc[2][8];
#pragma unroll
    for (int ng = 0; ng < 2; ++ng)
#pragma unroll
        for (int ct = 0; ct < 8; ++ct) Oc[ng][ct] = (f32x4){0.f, 0.f, 0.f, 0.f};
    float mold[2][4], lsum[2][4];
#pragma unroll
    for (int ng = 0; ng < 2; ++ng)
#pragma unroll
        for (int r = 0; r < 4; ++r) { mold[ng][r] = -1e30f; lsum[ng][r] = 0.f; }

    const u16* qbase = Qh + (size_t)(batch * NPB) * D;
    const u16* vbase = Vt + (size_t)batch * (D * NPB);
    const int  mq0   = wv * 1024;

#pragma unroll 2
    for (int it = 0; it < 32; ++it) {
        const int m0 = mq0 + it * 32;

        // ---- Q fragments (B-operand of S): lane -> m-row m0+mt*16+l15, 16B contiguous
        half8 qf[4][2];
#pragma unroll
        for (int mt = 0; mt < 2; ++mt) {
            const u16* qr = qbase + (size_t)(m0 + mt * 16 + l15) * D + l4 * 8;
#pragma unroll
            for (int kc = 0; kc < 4; ++kc)
                qf[kc][mt] = *(const half8*)(qr + kc * 32);
        }
        // ---- V fragments (B-operand of PV): lane -> c=ct*16+l15, 16B contiguous in m
        half8 vf[8];
#pragma unroll
        for (int ct = 0; ct < 8; ++ct)
            vf[ct] = *(const half8*)(vbase + (size_t)(ct * 16 + l15) * NPB
                                     + m0 + l4 * 8);

        // ---- S' = (K*log2e) @ Q^T for both n-groups (qf reused)
        f32x4 sacc[2][2];
#pragma unroll
        for (int ng = 0; ng < 2; ++ng)
#pragma unroll
            for (int mt = 0; mt < 2; ++mt)
                sacc[ng][mt] = (f32x4){0.f, 0.f, 0.f, 0.f};
#pragma unroll
        for (int kc = 0; kc < 4; ++kc)
#pragma unroll
            for (int ng = 0; ng < 2; ++ng)
#pragma unroll
                for (int mt = 0; mt < 2; ++mt)
                    sacc[ng][mt] = __builtin_amdgcn_mfma_f32_16x16x32_f16(
                        kf[kc][ng], qf[kc][mt], sacc[ng][mt], 0, 0, 0);

        // ---- online softmax (exp2 domain), per n-group
#pragma unroll
        for (int ng = 0; ng < 2; ++ng)
#pragma unroll
            for (int r = 0; r < 4; ++r) {
                const float rmax  = dpp_row_max(fmaxf(sacc[ng][0][r], sacc[ng][1][r]));
                const float mnew  = fmaxf(mold[ng][r], rmax);
                const float alpha = EXP2(mold[ng][r] - mnew);
                mold[ng][r] = mnew;
                const float p0 = EXP2(sacc[ng][0][r] - mnew);
                const float p1 = EXP2(sacc[ng][1][r] - mnew);
                lsum[ng][r] = lsum[ng][r] * alpha + p0 + p1;
#pragma unroll
                for (int ct = 0; ct < 8; ++ct) Oc[ng][ct][r] *= alpha;
                Ps[wv][ng][l4 * 4 + r][l15]      = __builtin_bit_cast(u16, (_Float16)p0);
                Ps[wv][ng][l4 * 4 + r][16 + l15] = __builtin_bit_cast(u16, (_Float16)p1);
            }
        WAIT_LDS();                          // lgkm only; global loads unaffected

        half8 pf[2];
#pragma unroll
        for (int ng = 0; ng < 2; ++ng)
            pf[ng] = *(const half8*)&Ps[wv][ng][l15][l4 * 8];
#pragma unroll
        for (int ct = 0; ct < 8; ++ct)
#pragma unroll
            for (int ng = 0; ng < 2; ++ng)
                Oc[ng][ct] = __builtin_amdgcn_mfma_f32_16x16x32_f16(
                    pf[ng], vf[ct], Oc[ng][ct], 0, 0, 0);
    }

    // ---- final per-row sums
#pragma unroll
    for (int ng = 0; ng < 2; ++ng)
#pragma unroll
        for (int r = 0; r < 4; ++r) lsum[ng][r] = dpp_row_sum(lsum[ng][r]);

    // ---- combine the 4 m-quarters
    __syncthreads();
    if (l15 == 0) {
#pragma unroll
        for (int ng = 0; ng < 2; ++ng)
#pragma unroll
            for (int r = 0; r < 4; ++r) {
                cmbM[(wv * 2 + ng) * 16 + l4 * 4 + r] = mold[ng][r];
                cmbL[(wv * 2 + ng) * 16 + l4 * 4 + r] = lsum[ng][r];
            }
    }
    if (wv > 0) {
#pragma unroll
        for (int ng = 0; ng < 2; ++ng)
#pragma unroll
            for (int ct = 0; ct < 8; ++ct)
#pragma unroll
                for (int r = 0; r < 4; ++r)
                    Obuf[wv - 1][ng][l4 * 4 + r][ct * 16 + l15] = Oc[ng][ct][r];
    }
    __syncthreads();

    if (wv == 0) {
#pragma unroll
        for (int ng = 0; ng < 2; ++ng) {
            float aq[4][4], invL[4];
#pragma unroll
            for (int r = 0; r < 4; ++r) {
                const int row = l4 * 4 + r;
                float M = cmbM[ng * 16 + row];
#pragma unroll
                for (int q = 1; q < 4; ++q)
                    M = fmaxf(M, cmbM[(q * 2 + ng) * 16 + row]);
                float L = 0.f;
#pragma unroll
                for (int q = 0; q < 4; ++q) {
                    aq[q][r] = EXP2(cmbM[(q * 2 + ng) * 16 + row] - M);
                    L += cmbL[(q * 2 + ng) * 16 + row] * aq[q][r];
                }
                invL[r] = 1.f / L;
            }
#pragma unroll
            for (int ct = 0; ct < 8; ++ct) {
#pragma unroll
                for (int r = 0; r < 4; ++r) {
                    const int row  = l4 * 4 + r;
                    const int c    = ct * 16 + l15;
                    const int grow = gr0 + ng * 16 + row;
                    const float val =
                        (Oc[ng][ct][r] * aq[0][r]
                         + Obuf[0][ng][row][c] * aq[1][r]
                         + Obuf[1][ng][row][c] * aq[2][r]
                         + Obuf[2][ng][row][c] * aq[3][r]) * invL[r]
                        + Sc[(size_t)grow * D + c];
                    out[(size_t)grow * D + c] = val;
                }
            }
        }
    }
}

extern "C" void kernel_launch(void* const* d_in, const int* in_sizes, int n_in,
                              void* d_out, int out_size, void* d_ws, size_t ws_size,
                              hipStream_t stream) {
    const float* x  = (const float*)d_in[0];
    const float* Wk = (const float*)d_in[1];
    const float* bk = (const float*)d_in[2];
    const float* Wq = (const float*)d_in[3];
    const float* bq = (const float*)d_in[4];
    const float* Wv = (const float*)d_in[5];
    const float* bv = (const float*)d_in[6];
    const float* Ws = (const float*)d_in[7];
    const float* bs = (const float*)d_in[8];
    float* out = (float*)d_out;

    u16*   Kh = (u16*)d_ws;                       // 4 MB fp16 (log2e-scaled)
    u16*   Qh = Kh + (size_t)BN * D;              // 4 MB fp16
    u16*   Vt = Qh + (size_t)BN * D;              // 4 MB fp16, [b][c][m]
    float* Sc = (float*)(Vt + (size_t)BN * D);    // 8 MB fp32
    u16*   Wt = (u16*)(Sc + (size_t)BN * D);      // 256 KB fp16 W^T (4 mats)

    prep_kernel<<<128, 256, 0, stream>>>(Wk, Wq, Wv, Ws, Wt);
    proj_kernel<<<512, 256, 0, stream>>>(x, Wt, bk, bq, bv, bs,
                                         Kh, Qh, Vt, Sc);
    attn_kernel<<<512, 256, 0, stream>>>(Kh, Qh, Vt, Sc, out);
}

// Round 11
// 200.797 us; speedup vs baseline: 1.1278x; 1.1278x over previous
//
#include <hip/hip_runtime.h>
#include <math.h>

typedef unsigned short u16;
typedef __attribute__((ext_vector_type(8))) _Float16 half8;    // 8 fp16
typedef __attribute__((ext_vector_type(4))) float    f32x4;

#define BATCH 4
#define NPB   4096      // pixels per batch (H*W)
#define BN    16384     // BATCH * NPB
#define CC    256       // input channels
#define D     128       // output channels (C/2)
#define LOG2E 1.44269504088896f

#if __has_builtin(__builtin_amdgcn_exp2f)
#define EXP2(x) __builtin_amdgcn_exp2f(x)
#else
#define EXP2(x) exp2f(x)
#endif

// 16-lane (DPP row) reductions on the VALU pipe — no LDS crossbar.
template<int CTRL>
__device__ __forceinline__ float dpp_mov(float x) {
    return __builtin_bit_cast(float, __builtin_amdgcn_update_dpp(
        __builtin_bit_cast(int, x), __builtin_bit_cast(int, x),
        CTRL, 0xf, 0xf, false));
}
__device__ __forceinline__ float dpp_row_max(float x) {
    x = fmaxf(x, dpp_mov<0x128>(x));   // row_ror:8
    x = fmaxf(x, dpp_mov<0x124>(x));   // row_ror:4
    x = fmaxf(x, dpp_mov<0x122>(x));   // row_ror:2
    x = fmaxf(x, dpp_mov<0x121>(x));   // row_ror:1
    return x;
}
__device__ __forceinline__ float dpp_row_sum(float x) {
    x += dpp_mov<0x128>(x);
    x += dpp_mov<0x124>(x);
    x += dpp_mov<0x122>(x);
    x += dpp_mov<0x121>(x);
    return x;
}

// ---------------------------------------------------------------------------
// Prep: W[mat] (f32 [256][128]) -> Wt[mat][c][k] fp16 (c-major, contiguous k).
// mat 0 (K) pre-scaled by log2e. 128 blocks x 256 threads x 4 elements.
// ---------------------------------------------------------------------------
__global__ __launch_bounds__(256) void prep_kernel(
    const float* __restrict__ Wk, const float* __restrict__ Wq,
    const float* __restrict__ Wv, const float* __restrict__ Ws,
    u16* __restrict__ Wt)
{
    const int f   = (blockIdx.x * 256 + threadIdx.x) * 4;   // flat output idx
    const int mat = f >> 15;
    const int rem = f & 32767;
    const int c   = rem >> 8;
    const int k0  = rem & 255;
    const float* W = (mat == 0) ? Wk : (mat == 1) ? Wq : (mat == 2) ? Wv : Ws;
    const float scale = (mat == 0) ? LOG2E : 1.0f;
    _Float16 t4[4];
#pragma unroll
    for (int i = 0; i < 4; ++i)
        t4[i] = (_Float16)(W[(size_t)(k0 + i) * D + c] * scale);
    *(uint2*)&Wt[(size_t)mat * 32768 + (size_t)c * 256 + k0] = *(const uint2*)t4;
}

// ---------------------------------------------------------------------------
// Projection: grid (128, 4) = 128-pixel x-tile x one matrix per block.
// x staged ONCE to fp16 LDS (coalesced flat float4 loads, one barrier);
// W-fragments = 16 contiguous 16-B loads from pre-transposed Wt, held in
// registers for the whole block; 128 MFMAs/wave.
//   by=0: K -> fp16 [n][128] (log2e baked into Wt+bias)  by=1: Q -> fp16
//   by=2: V -> fp16 [b][c][4096]                         by=3: Sc -> fp32
// by 0/1/3 use swapped operands (D[c][m]) for packed stores.
// ---------------------------------------------------------------------------
#define APJ 264         // As row pitch in u16 (528 B: 16B-aligned, 4-bank row shift)

__global__ __launch_bounds__(256, 2) void proj_kernel(
    const float* __restrict__ x, const u16* __restrict__ Wt,
    const float* __restrict__ bk, const float* __restrict__ bq,
    const float* __restrict__ bv, const float* __restrict__ bs,
    u16* __restrict__ Kh, u16* __restrict__ Qh,
    u16* __restrict__ Vt, float* __restrict__ Sc)
{
    __shared__ __align__(16) u16 As[128][APJ];   // 66 KB -> 2 blocks/CU

    const int tid = threadIdx.x;
    const int wv  = tid >> 6;
    const int l   = tid & 63;
    const int l15 = l & 15;
    const int l4  = l >> 4;
    const int by  = blockIdx.y;
    const int gm0 = blockIdx.x * 128;
    const int c0  = wv * 32;

    // ---- W fragments from Wt: wf[ct][kc], lane -> W[k=kc*32+l4*8..+8][c0+ct*16+l15]
    const u16* wb = Wt + (size_t)by * 32768 + (size_t)(c0 + l15) * 256 + l4 * 8;
    half8 wf[2][8];
#pragma unroll
    for (int ct = 0; ct < 2; ++ct)
#pragma unroll
        for (int kc = 0; kc < 8; ++kc)
            wf[ct][kc] = *(const half8*)(wb + ct * 16 * 256 + kc * 32);

    // ---- stage the 128x256 x-tile once (coalesced: thread t -> float4 i*256+t)
    {
        const float4* xg = (const float4*)(x + (size_t)gm0 * CC);
#pragma unroll 8
        for (int i = 0; i < 32; ++i) {
            const int f = i * 256 + tid;           // flat float4 index
            const float4 v = xg[f];
            const int row = f >> 6, col4 = f & 63;
            _Float16 h[4] = {(_Float16)v.x, (_Float16)v.y,
                             (_Float16)v.z, (_Float16)v.w};
            *(uint2*)&As[row][col4 * 4] = *(const uint2*)h;
        }
    }
    __syncthreads();

    f32x4 acc[8][2];
#pragma unroll
    for (int mt = 0; mt < 8; ++mt) {
        acc[mt][0] = (f32x4){0.f, 0.f, 0.f, 0.f};
        acc[mt][1] = (f32x4){0.f, 0.f, 0.f, 0.f};
    }

    if (by == 2) {
        for (int kc = 0; kc < 8; ++kc)
#pragma unroll
            for (int mt = 0; mt < 8; ++mt) {
                const half8 a = *(const half8*)&As[mt * 16 + l15][kc * 32 + l4 * 8];
                acc[mt][0] = __builtin_amdgcn_mfma_f32_16x16x32_f16(a, wf[0][kc], acc[mt][0], 0, 0, 0);
                acc[mt][1] = __builtin_amdgcn_mfma_f32_16x16x32_f16(a, wf[1][kc], acc[mt][1], 0, 0, 0);
            }
        // V: D[m][c]; fp16 transposed [batch][c][m], pack 4 consecutive m
        const float bb[2] = {bv[c0 + l15], bv[c0 + 16 + l15]};
        const int batch = gm0 >> 12;
        const int mb0   = (gm0 & 4095) + l4 * 4;
        u16* vbp = Vt + (size_t)batch * (D * NPB);
#pragma unroll
        for (int mt = 0; mt < 8; ++mt)
#pragma unroll
            for (int ct = 0; ct < 2; ++ct) {
                const int c = c0 + ct * 16 + l15;
                _Float16 t4[4];
#pragma unroll
                for (int r = 0; r < 4; ++r)
                    t4[r] = (_Float16)(acc[mt][ct][r] + bb[ct]);
                *(uint2*)&vbp[(size_t)c * NPB + mb0 + mt * 16] = *(const uint2*)t4;
            }
    } else {
        for (int kc = 0; kc < 8; ++kc)
#pragma unroll
            for (int mt = 0; mt < 8; ++mt) {
                const half8 a = *(const half8*)&As[mt * 16 + l15][kc * 32 + l4 * 8];
                acc[mt][0] = __builtin_amdgcn_mfma_f32_16x16x32_f16(wf[0][kc], a, acc[mt][0], 0, 0, 0);
                acc[mt][1] = __builtin_amdgcn_mfma_f32_16x16x32_f16(wf[1][kc], a, acc[mt][1], 0, 0, 0);
            }
        // swapped: D[c][m] — lane holds c = c0+ct*16+l4*4+r, m = gm0+mt*16+l15
        if (by == 3) {
            float bb2[2][4];
#pragma unroll
            for (int ct = 0; ct < 2; ++ct)
#pragma unroll
                for (int r = 0; r < 4; ++r)
                    bb2[ct][r] = bs[c0 + ct * 16 + l4 * 4 + r];
#pragma unroll
            for (int mt = 0; mt < 8; ++mt) {
                const int m = gm0 + mt * 16 + l15;
#pragma unroll
                for (int ct = 0; ct < 2; ++ct) {
                    float4 v;
                    v.x = acc[mt][ct][0] + bb2[ct][0];
                    v.y = acc[mt][ct][1] + bb2[ct][1];
                    v.z = acc[mt][ct][2] + bb2[ct][2];
                    v.w = acc[mt][ct][3] + bb2[ct][3];
                    *(float4*)&Sc[(size_t)m * D + c0 + ct * 16 + l4 * 4] = v;
                }
            }
        } else {
            const float* bsrc = (by == 0) ? bk : bq;
            const float scale = (by == 0) ? LOG2E : 1.0f;   // Wt already scaled
            u16* O = (by == 0) ? Kh : Qh;
            float bb2[2][4];
#pragma unroll
            for (int ct = 0; ct < 2; ++ct)
#pragma unroll
                for (int r = 0; r < 4; ++r)
                    bb2[ct][r] = bsrc[c0 + ct * 16 + l4 * 4 + r] * scale;
#pragma unroll
            for (int mt = 0; mt < 8; ++mt) {
                const int m = gm0 + mt * 16 + l15;
#pragma unroll
                for (int ct = 0; ct < 2; ++ct) {
                    _Float16 t4[4];
#pragma unroll
                    for (int r = 0; r < 4; ++r)
                        t4[r] = (_Float16)(acc[mt][ct][r] + bb2[ct][r]);
                    *(uint2*)&O[(size_t)m * D + c0 + ct * 16 + l4 * 4] =
                        *(const uint2*)t4;
                }
            }
        }
    }
}

// ---------------------------------------------------------------------------
// Flash attention (round-9 proven kernel, byte-identical). 512 blocks x 32
// n-rows; 4 waves = 2 n-grp x 2 m-half; exp2 domain, fp16 P/V, DPP reductions.
// ---------------------------------------------------------------------------
#define TM 32
#define QP 136          // Qs/Ks row pitch (u16)
#define VP 40           // Vs/Ps row pitch (u16)

__global__ __launch_bounds__(256) void attn_kernel(
    const u16* __restrict__ Kh, const u16* __restrict__ Qh,
    const u16* __restrict__ Vt, const float* __restrict__ Sc,
    float* __restrict__ out)
{
    __shared__ __align__(16) unsigned char smem[51712];
    u16 (*Ks)[QP]     = (u16(*)[QP])(smem);                 // 32 x 136 (fp16)
    u16 (*Qs)[TM][QP] = (u16(*)[TM][QP])(smem + 8704);      // 2 x 32 x 136 (fp16)
    u16 (*Vs)[D][VP]  = (u16(*)[D][VP])(smem + 26112);      // 2 x 128 x 40 (fp16)
    u16 (*Ps)[16][VP] = (u16(*)[16][VP])(smem + 46592);     // 4 x 16 x 40 (fp16)

    const int tid = threadIdx.x;
    const int wv  = tid >> 6;
    const int l   = tid & 63;
    const int l15 = l & 15;
    const int l4  = l >> 4;
    const int batch = blockIdx.x & 3;
    const int tile  = blockIdx.x >> 2;
    const int gr0   = batch * NPB + tile * 32;

    const int n16 = wv & 1;                 // n-group
    const int mh  = wv >> 1;                // m-half

    // ---- stage K tile (32 x 128 fp16, already log2e-scaled)
    {
        const int row = tid >> 3, ch = tid & 7;
        const uint4* src = (const uint4*)(Kh + (size_t)(gr0 + row) * D + ch * 16);
        *(uint4*)&Ks[row][ch * 16]     = src[0];
        *(uint4*)&Ks[row][ch * 16 + 8] = src[1];
    }
    __syncthreads();

    half8 kf[4];
#pragma unroll
    for (int kc = 0; kc < 4; ++kc)
        kf[kc] = *(const half8*)&Ks[n16 * 16 + l15][kc * 32 + l4 * 8];

    f32x4 Oc[8];
#pragma unroll
    for (int ct = 0; ct < 8; ++ct) Oc[ct] = (f32x4){0.f, 0.f, 0.f, 0.f};
    float mold[4], lsum[4];
#pragma unroll
    for (int r = 0; r < 4; ++r) { mold[r] = -1e30f; lsum[r] = 0.f; }

    const u16* qsrc = Qh + (size_t)(batch * NPB + wv * 2048) * D;   // wv<2 only
    const u16* vsrc = Vt + (size_t)batch * NPB * D;                 // c-major

    for (int it = 0; it < 64; ++it) {
        __syncthreads();
        const int m0 = it * TM;
        if (wv < 2) {
            const u16* s = qsrc + (size_t)m0 * D + l15 * 8;
#pragma unroll
            for (int j = 0; j < 8; ++j) {
                const int row = j * 4 + l4;
                const uint4 v = *(const uint4*)(s + (size_t)row * D);
                *(uint4*)&Qs[wv][row][l15 * 8] = v;
            }
        } else {
            const int h = wv - 2;
            const u16* s = vsrc + (size_t)(h * 2048 + m0) + (l & 3) * 8;
#pragma unroll
            for (int j = 0; j < 8; ++j) {
                const int cc = j * 16 + (l >> 2);
                const uint4 v = *(const uint4*)(s + (size_t)cc * NPB);
                *(uint4*)&Vs[h][cc][(l & 3) * 8] = v;
            }
        }
        __syncthreads();

        // ---- S' = (K*log2e) @ Q^T (fp16 MFMA, log2-domain scores)
        f32x4 sacc[2];
        sacc[0] = (f32x4){0.f, 0.f, 0.f, 0.f};
        sacc[1] = (f32x4){0.f, 0.f, 0.f, 0.f};
#pragma unroll
        for (int kc = 0; kc < 4; ++kc) {
#pragma unroll
            for (int mt = 0; mt < 2; ++mt) {
                const half8 qf =
                    *(const half8*)&Qs[mh][mt * 16 + l15][kc * 32 + l4 * 8];
                sacc[mt] = __builtin_amdgcn_mfma_f32_16x16x32_f16(
                    kf[kc], qf, sacc[mt], 0, 0, 0);
            }
        }

        // ---- online softmax (exp2 domain): DPP row-max, unconditional rescale
#pragma unroll
        for (int r = 0; r < 4; ++r) {
            const float rmax  = dpp_row_max(fmaxf(sacc[0][r], sacc[1][r]));
            const float mnew  = fmaxf(mold[r], rmax);
            const float alpha = EXP2(mold[r] - mnew);
            mold[r] = mnew;
            const float p0 = EXP2(sacc[0][r] - mnew);
            const float p1 = EXP2(sacc[1][r] - mnew);
            lsum[r] = lsum[r] * alpha + p0 + p1;
#pragma unroll
            for (int ct = 0; ct < 8; ++ct) Oc[ct][r] *= alpha;
            Ps[wv][l4 * 4 + r][l15]      = __builtin_bit_cast(u16, (_Float16)p0);
            Ps[wv][l4 * 4 + r][16 + l15] = __builtin_bit_cast(u16, (_Float16)p1);
        }
        asm volatile("s_waitcnt lgkmcnt(0)" ::: "memory");   // wave-private Ps

        const half8 pf = *(const half8*)&Ps[wv][l15][l4 * 8];
#pragma unroll
        for (int ct = 0; ct < 8; ++ct) {
            const half8 vf = *(const half8*)&Vs[mh][ct * 16 + l15][l4 * 8];
            Oc[ct] = __builtin_amdgcn_mfma_f32_16x16x32_f16(pf, vf, Oc[ct], 0, 0, 0);
        }
    }

    // ---- final per-row sum across the 16 column-lanes (once, DPP)
#pragma unroll
    for (int r = 0; r < 4; ++r) lsum[r] = dpp_row_sum(lsum[r]);

    // ---- combine the two m-halves (waves wv and wv^2 share rows)
    __syncthreads();
    float (*Obuf)[16][D] = (float(*)[16][D])(smem);         // aliases Ks/Qs
    float* cmbM = (float*)(smem + 26112);                   // aliases Vs
    float* cmbL = (float*)(smem + 26368);

    if (l15 == 0) {
#pragma unroll
        for (int r = 0; r < 4; ++r) {
            cmbM[wv * 16 + l4 * 4 + r] = mold[r];
            cmbL[wv * 16 + l4 * 4 + r] = lsum[r];
        }
    }
    if (mh == 1) {
#pragma unroll
        for (int ct = 0; ct < 8; ++ct)
#pragma unroll
            for (int r = 0; r < 4; ++r)
                Obuf[n16][l4 * 4 + r][ct * 16 + l15] = Oc[ct][r];
    }
    __syncthreads();

    if (mh == 0) {
        float f0[4], f1[4], invL[4];
#pragma unroll
        for (int r = 0; r < 4; ++r) {
            const int row = l4 * 4 + r;
            const float M1 = cmbM[(wv + 2) * 16 + row];
            const float L1 = cmbL[(wv + 2) * 16 + row];
            const float M  = fmaxf(mold[r], M1);
            const float a0 = EXP2(mold[r] - M);
            const float a1 = EXP2(M1 - M);
            f0[r] = a0; f1[r] = a1;
            invL[r] = 1.f / (lsum[r] * a0 + L1 * a1);
        }
#pragma unroll
        for (int ct = 0; ct < 8; ++ct) {
#pragma unroll
            for (int r = 0; r < 4; ++r) {
                const int row  = l4 * 4 + r;
                const int c    = ct * 16 + l15;
                const int grow = gr0 + n16 * 16 + row;
                const float val =
                    (Oc[ct][r] * f0[r] + Obuf[n16][row][c] * f1[r]) * invL[r]
                    + Sc[(size_t)grow * D + c];
                out[(size_t)grow * D + c] = val;
            }
        }
    }
}

extern "C" void kernel_launch(void* const* d_in, const int* in_sizes, int n_in,
                              void* d_out, int out_size, void* d_ws, size_t ws_size,
                              hipStream_t stream) {
    const float* x  = (const float*)d_in[0];
    const float* Wk = (const float*)d_in[1];
    const float* bk = (const float*)d_in[2];
    const float* Wq = (const float*)d_in[3];
    const float* bq = (const float*)d_in[4];
    const float* Wv = (const float*)d_in[5];
    const float* bv = (const float*)d_in[6];
    const float* Ws = (const float*)d_in[7];
    const float* bs = (const float*)d_in[8];
    float* out = (float*)d_out;

    u16*   Kh = (u16*)d_ws;                       // 4 MB fp16 (log2e-scaled)
    u16*   Qh = Kh + (size_t)BN * D;              // 4 MB fp16
    u16*   Vt = Qh + (size_t)BN * D;              // 4 MB fp16, [b][c][m]
    float* Sc = (float*)(Vt + (size_t)BN * D);    // 8 MB fp32
    u16*   Wt = (u16*)(Sc + (size_t)BN * D);      // 256 KB fp16 W^T (4 mats)

    prep_kernel<<<128, 256, 0, stream>>>(Wk, Wq, Wv, Ws, Wt);
    proj_kernel<<<dim3(128, 4), 256, 0, stream>>>(x, Wt, bk, bq, bv, bs,
                                                  Kh, Qh, Vt, Sc);
    attn_kernel<<<512, 256, 0, stream>>>(Kh, Qh, Vt, Sc, out);
}